// Round 8
// baseline (546.864 us; speedup 1.0000x reference)
//
#include <hip/hip_runtime.h>
#include <math.h>

#define TSTEPS 512
#define RPB 8
#define L2E  1.4426950408889634f
#define L2E2 2.8853900817779268f   // 2*log2(e)
#define HSTR 88                    // h row stride in shorts: 176B=44dw -> (3n+q)%8 spread, only free 2-way

typedef __attribute__((ext_vector_type(4))) short short4v;
typedef __attribute__((ext_vector_type(8))) short short8;
typedef __attribute__((ext_vector_type(4))) float f32x4;
typedef __bf16 bf16x8 __attribute__((ext_vector_type(8)));

__device__ __forceinline__ short f2bf(float f) {            // RNE float->bf16
    union { float f; unsigned u; } v; v.f = f;
    return (short)((v.u + 0x7FFFu + ((v.u >> 16) & 1u)) >> 16);
}
__device__ __forceinline__ float rcp_f(float x) { return __builtin_amdgcn_rcpf(x); }
__device__ __forceinline__ float ex2(float x)   { return __builtin_amdgcn_exp2f(x); }
__device__ __forceinline__ float sigm_p(float v) { return rcp_f(1.0f + ex2(-v)); }   // v = x*log2e
__device__ __forceinline__ float tanh_p(float v) {                                    // v = x*2log2e
    return fmaf(-2.0f, rcp_f(1.0f + ex2(v)), 1.0f);        // 1 - 2/(1+e^{2x})
}
__device__ __forceinline__ f32x4 mfma16(bf16x8 a, bf16x8 b, f32x4 c) {
    return __builtin_amdgcn_mfma_f32_16x16x32_bf16(a, b, c, 0, 0, 0);
}

// 256 blocks x 256 threads (4 waves). Both layers merged into ONE 16x16 MFMA
// tile via block-diagonal K-packing (K=224):
//   A rows 0-7  = [x_t (32) | h0^{t-1} (64) | 0 (128)]        -> L0 step t
//   A rows 8-15 = [0 (96)   | h0^{t-1} (64) | h1^{t-2} (64)]  -> L1 step t-1
// B rows 0-31 Wih0, 32-95 Whh0, 96-159 Wih1, 160-223 Whh1 (dense, registers).
// Zero A-blocks come from zero-padded LDS rows read at +/-8-row offsets.
// R7/R8: 88-short h row stride (kills the 8-way conflicts of stride 72);
// x A-frag pre-read before the barrier; parity handled by integer offsets
// (pointer ARRAYS into LDS fail to compile: addrspacecast static-init error).
__global__ __launch_bounds__(256)
void lstm_mfma_68547678044465(const float* __restrict__ x,
                              const float* __restrict__ Wih0, const float* __restrict__ Whh0,
                              const float* __restrict__ bih0, const float* __restrict__ bhh0,
                              const float* __restrict__ Wih1, const float* __restrict__ Whh1,
                              const float* __restrict__ bih1, const float* __restrict__ bhh1,
                              const float* __restrict__ ln_g, const float* __restrict__ ln_b,
                              const float* __restrict__ fcw, const float* __restrict__ fcb,
                              float* __restrict__ out)
{
    __shared__ __align__(16) short XB[2][8][16][40];    // x bf16; rows 8-15 always zero
    __shared__ __align__(16) short HA[2][24][HSTR];     // rows 0-7 zero | 8-15 h0 | 16-23 zero
    __shared__ __align__(16) short HC[2][16][HSTR];     // rows 0-7 zero | 8-15 h1
    __shared__ __align__(16) float HF[8][64];           // final h1 fp32 for LN

    const int tid  = threadIdx.x;
    const int wl   = tid >> 6;           // wave 0..3
    const int lane = tid & 63;
    const int n    = lane & 15;          // A row m / C col n
    const int q    = lane >> 4;          // k-quad / C row group
    const int rb   = blockIdx.x * RPB;
    const int cell = wl * 16 + n;        // h-dim cell 0..63

    // ---- B-fragments: 4 gate-tiles x 7 K-chunks, named registers ----
    auto loadB = [&](const float* wrow, float sc) -> bf16x8 {
        const float4 lo = *(const float4*)(wrow);
        const float4 hi = *(const float4*)(wrow + 4);
        short8 r;
        r[0] = f2bf(lo.x * sc); r[1] = f2bf(lo.y * sc);
        r[2] = f2bf(lo.z * sc); r[3] = f2bf(lo.w * sc);
        r[4] = f2bf(hi.x * sc); r[5] = f2bf(hi.y * sc);
        r[6] = f2bf(hi.z * sc); r[7] = f2bf(hi.w * sc);
        return (bf16x8)r;
    };
    const int g0 = cell, g1 = 64 + cell, g2 = 128 + cell, g3 = 192 + cell;
    const int ko = q * 8;
    const bf16x8 B0_0 = loadB(Wih0 + g0 * 32 + ko, L2E);
    const bf16x8 B0_1 = loadB(Whh0 + g0 * 64 + ko, L2E);
    const bf16x8 B0_2 = loadB(Whh0 + g0 * 64 + 32 + ko, L2E);
    const bf16x8 B0_3 = loadB(Wih1 + g0 * 64 + ko, L2E);
    const bf16x8 B0_4 = loadB(Wih1 + g0 * 64 + 32 + ko, L2E);
    const bf16x8 B0_5 = loadB(Whh1 + g0 * 64 + ko, L2E);
    const bf16x8 B0_6 = loadB(Whh1 + g0 * 64 + 32 + ko, L2E);
    const bf16x8 B1_0 = loadB(Wih0 + g1 * 32 + ko, L2E);
    const bf16x8 B1_1 = loadB(Whh0 + g1 * 64 + ko, L2E);
    const bf16x8 B1_2 = loadB(Whh0 + g1 * 64 + 32 + ko, L2E);
    const bf16x8 B1_3 = loadB(Wih1 + g1 * 64 + ko, L2E);
    const bf16x8 B1_4 = loadB(Wih1 + g1 * 64 + 32 + ko, L2E);
    const bf16x8 B1_5 = loadB(Whh1 + g1 * 64 + ko, L2E);
    const bf16x8 B1_6 = loadB(Whh1 + g1 * 64 + 32 + ko, L2E);
    const bf16x8 B2_0 = loadB(Wih0 + g2 * 32 + ko, L2E2);
    const bf16x8 B2_1 = loadB(Whh0 + g2 * 64 + ko, L2E2);
    const bf16x8 B2_2 = loadB(Whh0 + g2 * 64 + 32 + ko, L2E2);
    const bf16x8 B2_3 = loadB(Wih1 + g2 * 64 + ko, L2E2);
    const bf16x8 B2_4 = loadB(Wih1 + g2 * 64 + 32 + ko, L2E2);
    const bf16x8 B2_5 = loadB(Whh1 + g2 * 64 + ko, L2E2);
    const bf16x8 B2_6 = loadB(Whh1 + g2 * 64 + 32 + ko, L2E2);
    const bf16x8 B3_0 = loadB(Wih0 + g3 * 32 + ko, L2E);
    const bf16x8 B3_1 = loadB(Whh0 + g3 * 64 + ko, L2E);
    const bf16x8 B3_2 = loadB(Whh0 + g3 * 64 + 32 + ko, L2E);
    const bf16x8 B3_3 = loadB(Wih1 + g3 * 64 + ko, L2E);
    const bf16x8 B3_4 = loadB(Wih1 + g3 * 64 + 32 + ko, L2E);
    const bf16x8 B3_5 = loadB(Whh1 + g3 * 64 + ko, L2E);
    const bf16x8 B3_6 = loadB(Whh1 + g3 * 64 + 32 + ko, L2E);

    // ---- biases: per-lane layer select (q<2 -> L0 rows, q>=2 -> L1 rows) ----
    float b0, b1, b2, b3;
    if (q < 2) {
        b0 = (bih0[g0] + bhh0[g0]) * L2E;  b1 = (bih0[g1] + bhh0[g1]) * L2E;
        b2 = (bih0[g2] + bhh0[g2]) * L2E2; b3 = (bih0[g3] + bhh0[g3]) * L2E;
    } else {
        b0 = (bih1[g0] + bhh1[g0]) * L2E;  b1 = (bih1[g1] + bhh1[g1]) * L2E;
        b2 = (bih1[g2] + bhh1[g2]) * L2E2; b3 = (bih1[g3] + bhh1[g3]) * L2E;
    }

    // ---- zero all LDS (zero rows must stay zero; parity bufs start 0) ----
    { int* z = (int*)XB; for (int i = tid; i < 5120; i += 256) z[i] = 0; }
    { int* z = (int*)HA; for (int i = tid; i < 2 * 24 * HSTR / 2; i += 256) z[i] = 0; }
    { int* z = (int*)HC; for (int i = tid; i < 2 * 16 * HSTR / 2; i += 256) z[i] = 0; }

    // ---- x staging: lane -> (step ss, row sm, quad kq), 2 float4 per group ----
    const int ss = tid >> 5, sm = (tid >> 2) & 7, kq = tid & 3;
    const float* xrow = x + (size_t)(rb + sm) * (TSTEPS * 32);
    float4 xr0, xr1;
    auto xstore = [&](int buf) {
        short4v pa; pa[0] = f2bf(xr0.x); pa[1] = f2bf(xr0.y);
        pa[2] = f2bf(xr0.z); pa[3] = f2bf(xr0.w);
        *(short4v*)&XB[buf][ss][sm][kq * 4] = pa;
        short4v pb; pb[0] = f2bf(xr1.x); pb[1] = f2bf(xr1.y);
        pb[2] = f2bf(xr1.z); pb[3] = f2bf(xr1.w);
        *(short4v*)&XB[buf][ss][sm][kq * 4 + 16] = pb;
    };
    xr0 = *(const float4*)(xrow + ss * 32 + kq * 4);
    xr1 = *(const float4*)(xrow + ss * 32 + kq * 4 + 16);
    xstore(0);
    __syncthreads();

    float c0 = 0.0f, c1 = 0.0f, c2 = 0.0f, c3 = 0.0f;

    // loop-invariant addresses: single LDS base pointers, parity as int offset
    const int HA_SZ = 24 * HSTR;                    // shorts per HA parity buffer
    const int HC_SZ = 16 * HSTR;
    const int aX  = n * 40 + q * 8;                 // XB in-slot offset (shorts)
    const int aH1 = (8 + n) * HSTR + q * 8;         // HA rows 8+m
    const int aH2 = n * HSTR + q * 8;               // HA/HC rows m
    const short* haB = &HA[0][0][0];
    const short* hcB = &HC[0][0][0];
    short* hstB;                                    // h store base (parity 0 dest)
    int    hstSz;                                   // += parity * this
    {
        const int rowb = 8 + (q & 1) * 4;
        if (q < 2) { hstB = &HA[0][rowb][0] + cell; hstSz = HA_SZ; }
        else       { hstB = &HC[0][rowb][0] + cell; hstSz = HC_SZ; }
    }

    bf16x8 a0 = *(const bf16x8*)(&XB[0][0][0][0] + aX);   // x frag for it=0

#pragma unroll 1
    for (int it = 0; it <= TSTEPS; ++it) {
        const int p = it & 1;

        if (((it & 7) == 0) && (it + 8 < TSTEPS)) {            // prefetch next x group (HBM)
            const size_t o = (size_t)(it + 8 + ss) * 32 + kq * 4;
            xr0 = *(const float4*)(xrow + o);
            xr1 = *(const float4*)(xrow + o + 16);
        }

        // ---- h A-fragments (post-barrier); x frag a0 was pre-read ----
        const short* ha = haB + p * HA_SZ;
        const short* hc = hcB + p * HC_SZ;
        const bf16x8 a1 = *(const bf16x8*)(ha + aH1);          // h0 k 0-31  rows 0-7
        const bf16x8 a2 = *(const bf16x8*)(ha + aH1 + 32);     // h0 k 32-63 rows 0-7
        const bf16x8 a3 = *(const bf16x8*)(ha + aH2);          // h0 k 0-31  rows 8-15
        const bf16x8 a4 = *(const bf16x8*)(ha + aH2 + 32);     // h0 k 32-63 rows 8-15
        const bf16x8 a5 = *(const bf16x8*)(hc + aH2);          // h1 k 0-31  rows 8-15
        const bf16x8 a6 = *(const bf16x8*)(hc + aH2 + 32);     // h1 k 32-63 rows 8-15

        f32x4 A0 = {b0, b0, b0, b0}, A1 = {b1, b1, b1, b1},
              A2 = {b2, b2, b2, b2}, A3 = {b3, b3, b3, b3};
        // x-MFMAs first: a0 already resident, runs while h reads are in flight
        A0 = mfma16(a0, B0_0, A0); A1 = mfma16(a0, B1_0, A1);
        A2 = mfma16(a0, B2_0, A2); A3 = mfma16(a0, B3_0, A3);
        A0 = mfma16(a1, B0_1, A0); A1 = mfma16(a1, B1_1, A1);
        A2 = mfma16(a1, B2_1, A2); A3 = mfma16(a1, B3_1, A3);
        A0 = mfma16(a2, B0_2, A0); A1 = mfma16(a2, B1_2, A1);
        A2 = mfma16(a2, B2_2, A2); A3 = mfma16(a2, B3_2, A3);
        A0 = mfma16(a3, B0_3, A0); A1 = mfma16(a3, B1_3, A1);
        A2 = mfma16(a3, B2_3, A2); A3 = mfma16(a3, B3_3, A3);
        A0 = mfma16(a4, B0_4, A0); A1 = mfma16(a4, B1_4, A1);
        A2 = mfma16(a4, B2_4, A2); A3 = mfma16(a4, B3_4, A3);
        A0 = mfma16(a5, B0_5, A0); A1 = mfma16(a5, B1_5, A1);
        A2 = mfma16(a5, B2_5, A2); A3 = mfma16(a5, B3_5, A3);
        A0 = mfma16(a6, B0_6, A0); A1 = mfma16(a6, B1_6, A1);
        A2 = mfma16(a6, B2_6, A2); A3 = mfma16(a6, B3_6, A3);

        // ---- activations + c update (all lanes valid) ----
        const bool freeze = (it == 0) && (q >= 2);   // L1 phantom step -1
        float hv0, hv1, hv2, hv3;
        {
            const float iv = sigm_p(A0[0]), fv = sigm_p(A1[0]);
            const float gv = tanh_p(A2[0]), ov = sigm_p(A3[0]);
            const float cn = fmaf(fv, c0, iv * gv);
            c0 = freeze ? 0.0f : cn;
            hv0 = ov * tanh_p(c0 * L2E2);
        }
        {
            const float iv = sigm_p(A0[1]), fv = sigm_p(A1[1]);
            const float gv = tanh_p(A2[1]), ov = sigm_p(A3[1]);
            const float cn = fmaf(fv, c1, iv * gv);
            c1 = freeze ? 0.0f : cn;
            hv1 = ov * tanh_p(c1 * L2E2);
        }
        {
            const float iv = sigm_p(A0[2]), fv = sigm_p(A1[2]);
            const float gv = tanh_p(A2[2]), ov = sigm_p(A3[2]);
            const float cn = fmaf(fv, c2, iv * gv);
            c2 = freeze ? 0.0f : cn;
            hv2 = ov * tanh_p(c2 * L2E2);
        }
        {
            const float iv = sigm_p(A0[3]), fv = sigm_p(A1[3]);
            const float gv = tanh_p(A2[3]), ov = sigm_p(A3[3]);
            const float cn = fmaf(fv, c3, iv * gv);
            c3 = freeze ? 0.0f : cn;
            hv3 = ov * tanh_p(c3 * L2E2);
        }

        // ---- h store into parity p^1 ----
        {
            short* hd = hstB + (p ^ 1) * hstSz;
            if (!freeze) {
                hd[0]        = f2bf(hv0);
                hd[HSTR]     = f2bf(hv1);
                hd[2 * HSTR] = f2bf(hv2);
                hd[3 * HSTR] = f2bf(hv3);
            }
        }
        if ((it == TSTEPS) && (q >= 2)) {               // final h1 (step T-1), fp32
            const int rl = (q & 1) * 4;
            HF[rl + 0][cell] = hv0;
            HF[rl + 1][cell] = hv1;
            HF[rl + 2][cell] = hv2;
            HF[rl + 3][cell] = hv3;
        }

        if (((it & 7) == 6) && (it + 2 < TSTEPS)) xstore(((it >> 3) + 1) & 1);

        // pre-read next x frag while still pre-barrier (buffer stable unless group ends)
        if (((it & 7) != 7) && (it < TSTEPS))
            a0 = *(const bf16x8*)(&XB[(it >> 3) & 1][(it + 1) & 7][0][0] + aX);

        __syncthreads();

        if (((it & 7) == 7) && (it < TSTEPS))           // group boundary: new buffer, post-barrier
            a0 = *(const bf16x8*)(&XB[((it + 1) >> 3) & 1][0][0][0] + aX);
    }

    // ---- epilogue: LayerNorm + FC; each wave handles 2 rows ----
    const float lg = ln_g[lane], lb = ln_b[lane], fw = fcw[lane], fb = fcb[0];
#pragma unroll
    for (int rr = 0; rr < 2; ++rr) {
        const int row = wl * 2 + rr;
        const float v = HF[row][lane];
        float s1 = v, sq = v * v;
#pragma unroll
        for (int mm = 1; mm < 64; mm <<= 1) {
            s1 += __shfl_xor(s1, mm, 64);
            sq += __shfl_xor(sq, mm, 64);
        }
        const float mu = s1 * (1.0f / 64.0f);
        float var = sq * (1.0f / 64.0f) - mu * mu;
        var = fmaxf(var, 0.0f);
        const float rs = rsqrtf(var + 1e-5f);
        float pv = ((v - mu) * rs * lg + lb) * fw;
#pragma unroll
        for (int mm = 1; mm < 64; mm <<= 1) pv += __shfl_xor(pv, mm, 64);
        if (lane == 0) out[rb + row] = pv + fb;
    }
}

extern "C" void kernel_launch(void* const* d_in, const int* in_sizes, int n_in,
                              void* d_out, int out_size, void* d_ws, size_t ws_size,
                              hipStream_t stream) {
    const float* x    = (const float*)d_in[0];
    const float* Wih0 = (const float*)d_in[1];
    const float* Whh0 = (const float*)d_in[2];
    const float* bih0 = (const float*)d_in[3];
    const float* bhh0 = (const float*)d_in[4];
    const float* Wih1 = (const float*)d_in[5];
    const float* Whh1 = (const float*)d_in[6];
    const float* bih1 = (const float*)d_in[7];
    const float* bhh1 = (const float*)d_in[8];
    const float* ln_g = (const float*)d_in[9];
    const float* ln_b = (const float*)d_in[10];
    const float* fcw  = (const float*)d_in[11];
    const float* fcb  = (const float*)d_in[12];

    dim3 grid(2048 / RPB);    // 256 blocks -> 1 per CU
    dim3 block(256);          // 4 waves: 1 per SIMD
    hipLaunchKernelGGL(lstm_mfma_68547678044465, grid, block, 0, stream,
                       x, Wih0, Whh0, bih0, bhh0, Wih1, Whh1, bih1, bhh1,
                       ln_g, ln_b, fcw, fcb, (float*)d_out);
}